// Round 20
// baseline (228.154 us; speedup 1.0000x reference)
//
#include <hip/hip_runtime.h>
#include <hip/hip_bf16.h>

typedef __hip_bfloat16 bf16;
typedef __attribute__((ext_vector_type(8))) __bf16 bf16x8;
typedef __attribute__((ext_vector_type(4))) __bf16 bf16x4;
typedef __attribute__((ext_vector_type(4))) float f32x4;

constexpr int S_LEN = 2048;
constexpr int HID   = 2560;
constexpr int NH    = 40;
constexpr int QL    = 768;
constexpr int KVL   = 256;
constexpr int RD    = 32;
constexpr int ND    = 64;
constexpr int VD    = 64;
constexpr int QHD   = 96;                 // NOPE_D + ROPE_D
constexpr int QB_N  = NH * QHD;           // 3840
constexpr int KVB_N = NH * (ND + VD);     // 5120
constexpr int CKV_N = KVL + RD;           // 288
constexpr int AB_N  = QL + CKV_N;         // 1056 (fused qa|kva output cols)

#define MFMA16(a, b, c) __builtin_amdgcn_mfma_f32_16x16x32_bf16((a), (b), (c), 0, 0, 0)

// position_ids may arrive as int32 or int64; values are 0..2047 so sniff layout.
__device__ __forceinline__ int get_pos(const int* pos, int s) {
  bool is64 = (pos[1] == 0 && pos[2] == 1);
  return is64 ? pos[2 * s] : pos[s];
}

// ---------------- prep ----------------

__global__ void cast_f32_bf16(const float* __restrict__ src, bf16* __restrict__ dst, int n4) {
  int i = blockIdx.x * blockDim.x + threadIdx.x;
  if (i >= n4) return;
  float4 v = reinterpret_cast<const float4*>(src)[i];
  struct { bf16 a, b, c, d; } pk;
  pk.a = __float2bfloat16(v.x); pk.b = __float2bfloat16(v.y);
  pk.c = __float2bfloat16(v.z); pk.d = __float2bfloat16(v.w);
  reinterpret_cast<uint2*>(dst)[i] = *reinterpret_cast<uint2*>(&pk);
}

// src [K][N] f32 -> dst [N][K] bf16  (B^T layout for the GEMMs)
__global__ void transpose_cast(const float* __restrict__ src, bf16* __restrict__ dst, int K, int N) {
  __shared__ float tile[32][33];
  int nb = blockIdx.x * 32, kb = blockIdx.y * 32;
  int x = threadIdx.x, y = threadIdx.y; // (32,8)
#pragma unroll
  for (int j = 0; j < 4; ++j) {
    int k = kb + y + j * 8, n = nb + x;
    tile[y + j * 8][x] = (k < K && n < N) ? src[(size_t)k * N + n] : 0.f;
  }
  __syncthreads();
#pragma unroll
  for (int j = 0; j < 4; ++j) {
    int n = nb + y + j * 8, k = kb + x;
    if (n < N && k < K) dst[(size_t)n * K + k] = __float2bfloat16(tile[x][y + j * 8]);
  }
}

// ---------------- GEMMs ----------------

// Fused qa|kva GEMM: C[2048][1056] = hid_bf * wabT^T.
// BM=64 x BN=64 tiles -> 544 blocks. 4 waves, each 16 rows x 64 cols.
__global__ __launch_bounds__(256) void gemm_qakva(const bf16* __restrict__ A,
                                                  const bf16* __restrict__ B,
                                                  float* __restrict__ q_out,
                                                  float* __restrict__ ckv_out) {
  constexpr int BM = 64, BK = 64, K = HID, N = AB_N;
  __shared__ __bf16 ldsA[BM * BK]; // 8KB
  __shared__ __bf16 ldsB[64 * BK]; // 8KB
  const int t = threadIdx.x;
  const int l = t & 63, w = t >> 6;
  const int lr = l & 15, lk = l >> 4;
  const int rowbase = blockIdx.y * BM;
  const int colbase = blockIdx.x * 64;

  f32x4 acc[4];
#pragma unroll
  for (int n = 0; n < 4; ++n) acc[n] = f32x4{0.f, 0.f, 0.f, 0.f};

  for (int kt = 0; kt < K / BK; ++kt) {
    const int kb = kt * BK;
#pragma unroll
    for (int it = 0; it < 2; ++it) {
      const int r  = it * 32 + w * 8 + (l >> 3);
      const int c8 = ((l & 7) * 8) ^ ((r & 7) << 3);
      const bf16* ga = A + (size_t)(rowbase + r) * K + kb + c8;
      __builtin_amdgcn_global_load_lds((const __attribute__((address_space(1))) void*)ga,
          (__attribute__((address_space(3))) void*)(ldsA + it * 2048 + w * 512), 16, 0, 0);
      int nrow = colbase + r;
      nrow = (nrow < N) ? nrow : (N - 1);
      const bf16* gb = B + (size_t)nrow * K + kb + c8;
      __builtin_amdgcn_global_load_lds((const __attribute__((address_space(1))) void*)gb,
          (__attribute__((address_space(3))) void*)(ldsB + it * 2048 + w * 512), 16, 0, 0);
    }
    __syncthreads();
#pragma unroll
    for (int kk = 0; kk < 2; ++kk) {
      const int arow = w * 16 + lr;
      const int ace  = (kk * 32 + lk * 8) ^ ((arow & 7) << 3);
      bf16x8 af = *(const bf16x8*)(ldsA + arow * BK + ace);
#pragma unroll
      for (int n = 0; n < 4; ++n) {
        const int row = n * 16 + lr;
        const int ce  = (kk * 32 + lk * 8) ^ ((row & 7) << 3);
        bf16x8 bfr = *(const bf16x8*)(ldsB + row * BK + ce);
        acc[n] = MFMA16(af, bfr, acc[n]);
      }
    }
    __syncthreads();
  }

#pragma unroll
  for (int n = 0; n < 4; ++n) {
    const int col = colbase + n * 16 + lr;
#pragma unroll
    for (int i = 0; i < 4; ++i) {
      const int row = rowbase + w * 16 + lk * 4 + i;
      if (col < QL)       q_out[(size_t)row * QL + col] = acc[n][i];
      else if (col < N)   ckv_out[(size_t)row * CKV_N + (col - QL)] = acc[n][i];
    }
  }
}

// Output projection: out[2048][2560] = ctx * woT^T, BM=128 x BN=64 tiles.
__global__ __launch_bounds__(256) void gemm_out64(const bf16* __restrict__ A,
                                                  const bf16* __restrict__ B,
                                                  float* __restrict__ C) {
  constexpr int BM = 128, BK = 64, K = HID, N = HID;
  __shared__ __bf16 ldsA[BM * BK];
  __shared__ __bf16 ldsB[64 * BK];
  const int t = threadIdx.x;
  const int l = t & 63, w = t >> 6;
  const int lr = l & 15, lk = l >> 4;
  const int rowbase = blockIdx.y * BM;
  const int colbase = blockIdx.x * 64;

  f32x4 acc[2][4];
#pragma unroll
  for (int m = 0; m < 2; ++m)
#pragma unroll
    for (int n = 0; n < 4; ++n) acc[m][n] = f32x4{0.f, 0.f, 0.f, 0.f};

  for (int kt = 0; kt < K / BK; ++kt) {
    const int kb = kt * BK;
#pragma unroll
    for (int it = 0; it < 4; ++it) {
      const int r  = it * 32 + w * 8 + (l >> 3);
      const int c8 = ((l & 7) * 8) ^ ((r & 7) << 3);
      const bf16* ga = A + (size_t)(rowbase + r) * K + kb + c8;
      __builtin_amdgcn_global_load_lds((const __attribute__((address_space(1))) void*)ga,
          (__attribute__((address_space(3))) void*)(ldsA + it * 2048 + w * 512), 16, 0, 0);
      if (it < 2) {
        const bf16* gb = B + (size_t)(colbase + r) * K + kb + c8;
        __builtin_amdgcn_global_load_lds((const __attribute__((address_space(1))) void*)gb,
            (__attribute__((address_space(3))) void*)(ldsB + it * 2048 + w * 512), 16, 0, 0);
      }
    }
    __syncthreads();
#pragma unroll
    for (int kk = 0; kk < 2; ++kk) {
      bf16x8 af[2], bfr[4];
#pragma unroll
      for (int m = 0; m < 2; ++m) {
        const int row = w * 32 + m * 16 + lr;
        const int ce  = (kk * 32 + lk * 8) ^ ((row & 7) << 3);
        af[m] = *(const bf16x8*)(ldsA + row * BK + ce);
      }
#pragma unroll
      for (int n = 0; n < 4; ++n) {
        const int row = n * 16 + lr;
        const int ce  = (kk * 32 + lk * 8) ^ ((row & 7) << 3);
        bfr[n] = *(const bf16x8*)(ldsB + row * BK + ce);
      }
#pragma unroll
      for (int m = 0; m < 2; ++m)
#pragma unroll
        for (int n = 0; n < 4; ++n)
          acc[m][n] = MFMA16(af[m], bfr[n], acc[m][n]);
    }
    __syncthreads();
  }

#pragma unroll
  for (int m = 0; m < 2; ++m)
#pragma unroll
    for (int n = 0; n < 4; ++n) {
      const int col = colbase + n * 16 + lr;
#pragma unroll
      for (int i = 0; i < 4; ++i) {
        const int row = rowbase + w * 32 + m * 16 + lk * 4 + i;
        C[(size_t)row * N + col] = acc[m][n][i];
      }
    }
}

// qb GEMM with fused RoPE + scale, writing qfull [NH][S][96] directly.
// BM=128 x BN=64 -> 960 blocks.
__global__ __launch_bounds__(256) void gemm_qb_rope(const bf16* __restrict__ A,
                                                    const bf16* __restrict__ B,
                                                    const float* __restrict__ ropc,
                                                    const float* __restrict__ rops,
                                                    bf16* __restrict__ qfull) {
  constexpr int BM = 128, BK = 64, K = QL;
  __shared__ __bf16 ldsA[BM * BK];
  __shared__ __bf16 ldsB[64 * BK];
  const int t = threadIdx.x;
  const int l = t & 63, w = t >> 6;
  const int lr = l & 15, lk = l >> 4;
  const int rowbase = blockIdx.y * BM;
  const int colbase = blockIdx.x * 64;
  const float scale = 0.14724444f; // 96^-0.5 * log2(e)

  f32x4 acc[2][4];
#pragma unroll
  for (int m = 0; m < 2; ++m)
#pragma unroll
    for (int n = 0; n < 4; ++n) acc[m][n] = f32x4{0.f, 0.f, 0.f, 0.f};

  for (int kt = 0; kt < K / BK; ++kt) {
    const int kb = kt * BK;
#pragma unroll
    for (int it = 0; it < 4; ++it) {
      const int r  = it * 32 + w * 8 + (l >> 3);
      const int c8 = ((l & 7) * 8) ^ ((r & 7) << 3);
      const bf16* ga = A + (size_t)(rowbase + r) * K + kb + c8;
      __builtin_amdgcn_global_load_lds((const __attribute__((address_space(1))) void*)ga,
          (__attribute__((address_space(3))) void*)(ldsA + it * 2048 + w * 512), 16, 0, 0);
      if (it < 2) {
        const bf16* gb = B + (size_t)(colbase + r) * K + kb + c8;
        __builtin_amdgcn_global_load_lds((const __attribute__((address_space(1))) void*)gb,
            (__attribute__((address_space(3))) void*)(ldsB + it * 2048 + w * 512), 16, 0, 0);
      }
    }
    __syncthreads();
#pragma unroll
    for (int kk = 0; kk < 2; ++kk) {
      bf16x8 af[2], bfr[4];
#pragma unroll
      for (int m = 0; m < 2; ++m) {
        const int row = w * 32 + m * 16 + lr;
        const int ce  = (kk * 32 + lk * 8) ^ ((row & 7) << 3);
        af[m] = *(const bf16x8*)(ldsA + row * BK + ce);
      }
#pragma unroll
      for (int n = 0; n < 4; ++n) {
        const int row = n * 16 + lr;
        const int ce  = (kk * 32 + lk * 8) ^ ((row & 7) << 3);
        bfr[n] = *(const bf16x8*)(ldsB + row * BK + ce);
      }
#pragma unroll
      for (int m = 0; m < 2; ++m)
#pragma unroll
        for (int n = 0; n < 4; ++n)
          acc[m][n] = MFMA16(af[m], bfr[n], acc[m][n]);
    }
    __syncthreads();
  }

#pragma unroll
  for (int m = 0; m < 2; ++m) {
    const int rowtop = rowbase + w * 32 + m * 16 + lk * 4;
#pragma unroll
    for (int n = 0; n < 4; ++n) {
      const int c0 = colbase + n * 16; // frag base col
      const int h  = c0 / 96;
      const int d0 = c0 - h * 96;
      const size_t qb_ = ((size_t)h * S_LEN + rowtop) * QHD + d0 + lr;
      if (d0 < ND) {
#pragma unroll
        for (int i = 0; i < 4; ++i)
          qfull[qb_ + (size_t)i * QHD] = __float2bfloat16(acc[m][n][i] * scale);
      } else if (d0 == ND) { // rope-lo: out = x0*c - x1*s, x1 = acc[m][n+1]
#pragma unroll
        for (int i = 0; i < 4; ++i) {
          const float c = ropc[(rowtop + i) * 16 + lr];
          const float s = rops[(rowtop + i) * 16 + lr];
          const float x0 = acc[m][n][i], x1 = acc[m][n + 1][i];
          qfull[qb_ + (size_t)i * QHD] = __float2bfloat16((x0 * c - x1 * s) * scale);
        }
      } else { // d0 == 80, rope-hi: out = x1*c + x0*s, x0 = acc[m][n-1]
#pragma unroll
        for (int i = 0; i < 4; ++i) {
          const float c = ropc[(rowtop + i) * 16 + lr];
          const float s = rops[(rowtop + i) * 16 + lr];
          const float x1 = acc[m][n][i], x0 = acc[m][n - 1][i];
          qfull[qb_ + (size_t)i * QHD] = __float2bfloat16((x1 * c + x0 * s) * scale);
        }
      }
    }
  }
}

// kvb GEMM writing k_nope into kfull[h][s][0:64] (stride 96) and vt [NH][64][S].
__global__ __launch_bounds__(256) void gemm_kvb_split(const bf16* __restrict__ A,
                                                      const bf16* __restrict__ B,
                                                      bf16* __restrict__ kfull,
                                                      bf16* __restrict__ vt) {
  constexpr int BM = 128, BN = 128, BK = 64, K = KVL;
  __shared__ __bf16 ldsA[BM * BK];
  __shared__ __bf16 ldsB[BN * BK];
  const int t = threadIdx.x;
  const int l = t & 63, w = t >> 6;
  const int lr = l & 15, lk = l >> 4;
  const int wr = w >> 1, wc = w & 1;
  const int rowbase = blockIdx.y * BM;
  const int h = blockIdx.x; // head == col tile
  const int colbase = h * BN;

  f32x4 acc[4][4];
#pragma unroll
  for (int m = 0; m < 4; ++m)
#pragma unroll
    for (int n = 0; n < 4; ++n) acc[m][n] = f32x4{0.f, 0.f, 0.f, 0.f};

  for (int kt = 0; kt < K / BK; ++kt) {
    const int kb = kt * BK;
#pragma unroll
    for (int it = 0; it < 4; ++it) {
      const int r  = it * 32 + w * 8 + (l >> 3);
      const int c8 = ((l & 7) * 8) ^ ((r & 7) << 3);
      const bf16* ga = A + (size_t)(rowbase + r) * K + kb + c8;
      __builtin_amdgcn_global_load_lds((const __attribute__((address_space(1))) void*)ga,
          (__attribute__((address_space(3))) void*)(ldsA + it * 2048 + w * 512), 16, 0, 0);
      const bf16* gb = B + (size_t)(colbase + r) * K + kb + c8;
      __builtin_amdgcn_global_load_lds((const __attribute__((address_space(1))) void*)gb,
          (__attribute__((address_space(3))) void*)(ldsB + it * 2048 + w * 512), 16, 0, 0);
    }
    __syncthreads();
#pragma unroll
    for (int kk = 0; kk < 2; ++kk) {
      bf16x8 af[4], bfr[4];
#pragma unroll
      for (int m = 0; m < 4; ++m) {
        const int row = wr * 64 + m * 16 + lr;
        const int ce  = (kk * 32 + lk * 8) ^ ((row & 7) << 3);
        af[m] = *(const bf16x8*)(ldsA + row * BK + ce);
      }
#pragma unroll
      for (int n = 0; n < 4; ++n) {
        const int row = wc * 64 + n * 16 + lr;
        const int ce  = (kk * 32 + lk * 8) ^ ((row & 7) << 3);
        bfr[n] = *(const bf16x8*)(ldsB + row * BK + ce);
      }
#pragma unroll
      for (int m = 0; m < 4; ++m)
#pragma unroll
        for (int n = 0; n < 4; ++n)
          acc[m][n] = MFMA16(af[m], bfr[n], acc[m][n]);
    }
    __syncthreads();
  }

#pragma unroll
  for (int m = 0; m < 4; ++m) {
    const int rowtop = rowbase + wr * 64 + m * 16 + lk * 4;
    if (wc == 0) { // k_nope -> kfull[h][s][0:64] (stride QHD)
#pragma unroll
      for (int n = 0; n < 4; ++n) {
        const int d = n * 16 + lr;
#pragma unroll
        for (int i = 0; i < 4; ++i)
          kfull[((size_t)h * S_LEN + rowtop + i) * QHD + d] = __float2bfloat16(acc[m][n][i]);
      }
    } else {        // V -> vt[h][64][S] (8B transposed stores, L2 merges)
#pragma unroll
      for (int n = 0; n < 4; ++n) {
        const int d = n * 16 + lr;
        bf16x4 pk;
#pragma unroll
        for (int i = 0; i < 4; ++i) pk[i] = (__bf16)acc[m][n][i];
        *(bf16x4*)(vt + ((size_t)h * VD + d) * S_LEN + rowtop) = pk;
      }
    }
  }
}

// ---------------- norms / prep ----------------

__global__ void rmsnorm_rows(const float* __restrict__ in, const float* __restrict__ w,
                             bf16* __restrict__ out, int C) {
  const int r = blockIdx.x;
  const float* row = in + (size_t)r * C;
  float ss = 0.f;
  for (int c = threadIdx.x; c < C; c += 256) { float v = row[c]; ss += v * v; }
#pragma unroll
  for (int d = 32; d > 0; d >>= 1) ss += __shfl_xor(ss, d);
  __shared__ float red[4];
  if ((threadIdx.x & 63) == 0) red[threadIdx.x >> 6] = ss;
  __syncthreads();
  const float tot = red[0] + red[1] + red[2] + red[3];
  const float rs = rsqrtf(tot / (float)C + 1e-6f);
  for (int c = threadIdx.x; c < C; c += 256)
    out[(size_t)r * C + c] = __float2bfloat16(row[c] * rs * w[c]);
}

// per row: rmsnorm(ckv[0:256]) -> bf16 ; rope(k_pe) broadcast into
// kfull[h][s][64:96] for ALL heads (via LDS); rope tables for the q path.
__global__ void kv_prep(const float* __restrict__ ckv, const float* __restrict__ w,
                        const int* __restrict__ pos, bf16* __restrict__ ckv_bf,
                        bf16* __restrict__ kfull, float* __restrict__ ropc,
                        float* __restrict__ rops) {
  const int s = blockIdx.x, t = threadIdx.x; // 64 threads
  __shared__ bf16 pe_lds[32];
  const float* row = ckv + (size_t)s * CKV_N;
  float v[4]; float ss = 0.f;
#pragma unroll
  for (int j = 0; j < 4; ++j) { v[j] = row[t + 64 * j]; ss += v[j] * v[j]; }
#pragma unroll
  for (int d = 32; d > 0; d >>= 1) ss += __shfl_xor(ss, d);
  const float rs = rsqrtf(ss / (float)KVL + 1e-6f);
#pragma unroll
  for (int j = 0; j < 4; ++j)
    ckv_bf[(size_t)s * KVL + t + 64 * j] = __float2bfloat16(v[j] * rs * w[t + 64 * j]);
  if (t < 16) {
    const float x0 = row[KVL + t], x1 = row[KVL + 16 + t];
    const float p = (float)get_pos(pos, s);
    const float invf = exp2f(-(float)t * (13.2877124f / 16.f)); // 10000^(-t/16)
    const float ang = p * invf, c = cosf(ang), sn = sinf(ang);
    ropc[s * 16 + t] = c;
    rops[s * 16 + t] = sn;
    pe_lds[t]      = __float2bfloat16(x0 * c - x1 * sn);
    pe_lds[16 + t] = __float2bfloat16(x1 * c + x0 * sn);
  }
  __syncthreads();
  // broadcast pe into every head's kfull row (coalesced 64B per 32-lane group)
  for (int idx = t; idx < NH * 32; idx += 64) {
    const int h = idx >> 5, d = idx & 31;
    kfull[((size_t)h * S_LEN + s) * QHD + ND + d] = pe_lds[d];
  }
}

// ---------------- causal flash attention ----------------
// One wave per block, 32 q rows, KVBLK=64, SWAPPED QK^T, log2-domain softmax,
// shuffle-free steady state, XOR-swizzled P tile, V double-buffered.
// SOFTWARE PIPELINE (T15-style): QK^T for tile n+1 is computed at the TOP of
// iteration n, so its MFMAs retire on the matrix pipe WHILE the VALU runs
// softmax(st_n) and PV(n) — per-iteration critical path becomes
// max(QK, softmax+PV) instead of their sum. K load depth stays 1 tile
// (K(n+2) issued after K(n+1) is consumed). Grid (NH, 64), q-tiles REVERSED.
__global__ __launch_bounds__(64) void attn_kernel(const bf16* __restrict__ qfull,
                                                  const bf16* __restrict__ kfull,
                                                  const bf16* __restrict__ vt,
                                                  bf16* __restrict__ ctx) {
  const int h = blockIdx.x;
  const int qw = ((int)gridDim.y - 1 - (int)blockIdx.y) * 32;
  const int l = threadIdx.x;
  const int lr = l & 15, lk = l >> 4;
  const bf16* Q  = qfull + (size_t)h * S_LEN * QHD;
  const bf16* Kf = kfull + (size_t)h * S_LEN * QHD;
  const bf16* V  = vt + (size_t)h * VD * S_LEN;
  __shared__ __bf16 plds[32][64]; // XOR-swizzled: col ^= (lr&7)<<3

  bf16x8 qf[2][3];
#pragma unroll
  for (int qg = 0; qg < 2; ++qg)
#pragma unroll
    for (int ks = 0; ks < 3; ++ks)
      qf[qg][ks] = *(const bf16x8*)(Q + (size_t)(qw + qg * 16 + lr) * QHD + ks * 32 + lk * 8);

  f32x4 o[2][4];
  float mrow[2], lrow[2]; // lrow is LANE-PARTIAL
#pragma unroll
  for (int qg = 0; qg < 2; ++qg) {
#pragma unroll
    for (int dt = 0; dt < 4; ++dt) o[qg][dt] = f32x4{0.f, 0.f, 0.f, 0.f};
    mrow[qg] = -1e30f; lrow[qg] = 0.f;
  }

  const int nt = (qw >> 6) + 1; // number of 64-wide k tiles

  // prologue: K0, V0 loads; st_cur = QK(K0); then K1 load
  bf16x8 kf[4][3];
#pragma unroll
  for (int sub = 0; sub < 4; ++sub)
#pragma unroll
    for (int ks = 0; ks < 3; ++ks)
      kf[sub][ks] = *(const bf16x8*)(Kf + (size_t)(sub * 16 + lr) * QHD + ks * 32 + lk * 8);
  bf16x8 vA[2][4];
#pragma unroll
  for (int h2 = 0; h2 < 2; ++h2)
#pragma unroll
    for (int dt = 0; dt < 4; ++dt)
      vA[h2][dt] = *(const bf16x8*)(V + (size_t)(dt * 16 + lr) * S_LEN + h2 * 32 + lk * 8);

  f32x4 stc[2][4];
#pragma unroll
  for (int qg = 0; qg < 2; ++qg)
#pragma unroll
    for (int sub = 0; sub < 4; ++sub) stc[qg][sub] = f32x4{0.f, 0.f, 0.f, 0.f};
  __builtin_amdgcn_s_setprio(1);
#pragma unroll
  for (int qg = 0; qg < 2; ++qg)
#pragma unroll
    for (int sub = 0; sub < 4; ++sub)
#pragma unroll
      for (int ks = 0; ks < 3; ++ks)
        stc[qg][sub] = MFMA16(kf[sub][ks], qf[qg][ks], stc[qg][sub]);
  __builtin_amdgcn_s_setprio(0);

  if (nt > 1) { // K tile 1
#pragma unroll
    for (int sub = 0; sub < 4; ++sub)
#pragma unroll
      for (int ks = 0; ks < 3; ++ks)
        kf[sub][ks] = *(const bf16x8*)(Kf + (size_t)(64 + sub * 16 + lr) * QHD + ks * 32 + lk * 8);
  }

  for (int ti = 0; ti < nt; ++ti) {
    const int kb = ti * 64;
    const bool more = (ti + 1 < nt);

    // issue NEXT tile's V loads
    bf16x8 vB[2][4];
    if (more) {
#pragma unroll
      for (int h2 = 0; h2 < 2; ++h2)
#pragma unroll
        for (int dt = 0; dt < 4; ++dt)
          vB[h2][dt] = *(const bf16x8*)(V + (size_t)(dt * 16 + lr) * S_LEN + (kb + 64) + h2 * 32 + lk * 8);
    }

    // PIPELINED: compute NEXT tile's scores now (kf holds K(kb+64));
    // these MFMAs retire while the VALU below runs softmax(stc) + PV.
    f32x4 stn[2][4];
    if (more) {
#pragma unroll
      for (int qg = 0; qg < 2; ++qg)
#pragma unroll
        for (int sub = 0; sub < 4; ++sub) stn[qg][sub] = f32x4{0.f, 0.f, 0.f, 0.f};
      __builtin_amdgcn_s_setprio(1);
#pragma unroll
      for (int qg = 0; qg < 2; ++qg)
#pragma unroll
        for (int sub = 0; sub < 4; ++sub)
#pragma unroll
          for (int ks = 0; ks < 3; ++ks)
            stn[qg][sub] = MFMA16(kf[sub][ks], qf[qg][ks], stn[qg][sub]);
      __builtin_amdgcn_s_setprio(0);
    }

    // issue K(kb+128) into kf (consumed above; WAR handled by compiler)
    if (ti + 2 < nt) {
#pragma unroll
      for (int sub = 0; sub < 4; ++sub)
#pragma unroll
        for (int ks = 0; ks < 3; ++ks)
          kf[sub][ks] = *(const bf16x8*)(Kf + (size_t)(kb + 128 + sub * 16 + lr) * QHD + ks * 32 + lk * 8);
    }

    // causal mask (only possible on the last tile)
    float lmax[2];
#pragma unroll
    for (int qg = 0; qg < 2; ++qg) {
      const int q = qw + qg * 16 + lr;
      if (!more) {
#pragma unroll
        for (int sub = 0; sub < 4; ++sub)
#pragma unroll
          for (int i = 0; i < 4; ++i)
            if (kb + sub * 16 + lk * 4 + i > q) stc[qg][sub][i] = -1e30f;
      }
      float m0 = -1e30f;
#pragma unroll
      for (int sub = 0; sub < 4; ++sub)
#pragma unroll
        for (int i = 0; i < 4; ++i) m0 = fmaxf(m0, stc[qg][sub][i]);
      lmax[qg] = m0; // lane-local max (NOT reduced)
    }

    // defer-rescale gate on lane-local maxima (== global-max check via __all)
    const bool noresc = __all((lmax[0] <= mrow[0] + 8.f) && (lmax[1] <= mrow[1] + 8.f));
    float mnew[2], fac[2];
    if (noresc) {
      mnew[0] = mrow[0]; mnew[1] = mrow[1];
    } else { // rare path: full cross-lane reduce + rescale factors
#pragma unroll
      for (int qg = 0; qg < 2; ++qg) {
        float t0 = lmax[qg];
        t0 = fmaxf(t0, __shfl_xor(t0, 16));
        t0 = fmaxf(t0, __shfl_xor(t0, 32));
        mnew[qg] = fmaxf(mrow[qg], t0);
        fac[qg] = exp2f(mrow[qg] - mnew[qg]);
        mrow[qg] = mnew[qg];
      }
    }

#pragma unroll
    for (int qg = 0; qg < 2; ++qg) {
      float ts = 0.f;
#pragma unroll
      for (int sub = 0; sub < 4; ++sub) {
        bf16x4 pk;
#pragma unroll
        for (int i = 0; i < 4; ++i) {
          const float p = exp2f(stc[qg][sub][i] - mnew[qg]);
          ts += p;
          pk[i] = (__bf16)p;
        }
        const int swc = (sub * 16 + lk * 4) ^ ((lr & 7) << 3);
        *(bf16x4*)(&plds[qg * 16 + lr][swc]) = pk;
      }
      if (noresc) lrow[qg] += ts;
      else        lrow[qg] = lrow[qg] * fac[qg] + ts;
    }
    if (!noresc) {
#pragma unroll
      for (int qg = 0; qg < 2; ++qg)
#pragma unroll
        for (int i = 0; i < 4; ++i) {
          const float fr = __shfl(fac[qg], lk * 4 + i);
#pragma unroll
          for (int dt = 0; dt < 4; ++dt) o[qg][dt][i] *= fr;
        }
    }

    // PV: A = P from LDS (swizzled read), B = V frags prefetched last tile
#pragma unroll
    for (int h2 = 0; h2 < 2; ++h2) {
      const int swc = (h2 * 32 + lk * 8) ^ ((lr & 7) << 3);
      bf16x8 pa0 = *(const bf16x8*)(&plds[lr][swc]);
      bf16x8 pa1 = *(const bf16x8*)(&plds[16 + lr][swc]);
      __builtin_amdgcn_s_setprio(1);
#pragma unroll
      for (int dt = 0; dt < 4; ++dt) {
        o[0][dt] = MFMA16(pa0, vA[h2][dt], o[0][dt]);
        o[1][dt] = MFMA16(pa1, vA[h2][dt], o[1][dt]);
      }
      __builtin_amdgcn_s_setprio(0);
    }

    if (more) {
      // rotate pipeline state
#pragma unroll
      for (int qg = 0; qg < 2; ++qg)
#pragma unroll
        for (int sub = 0; sub < 4; ++sub) stc[qg][sub] = stn[qg][sub];
#pragma unroll
      for (int h2 = 0; h2 < 2; ++h2)
#pragma unroll
        for (int dt = 0; dt < 4; ++dt) vA[h2][dt] = vB[h2][dt];
    }
  }

  // epilogue: reduce lane-partial l (once), broadcast 1/l to o-row owners
#pragma unroll
  for (int qg = 0; qg < 2; ++qg) {
    float ls = lrow[qg];
    ls += __shfl_xor(ls, 16);
    ls += __shfl_xor(ls, 32);
    const float linv = 1.0f / ls;
#pragma unroll
    for (int i = 0; i < 4; ++i) {
      const float inv = __shfl(linv, lk * 4 + i);
#pragma unroll
      for (int dt = 0; dt < 4; ++dt) {
        const int row = qw + qg * 16 + lk * 4 + i;
        const int col = h * VD + dt * 16 + lr;
        ctx[(size_t)row * HID + col] = __float2bfloat16(o[qg][dt][i] * inv);
      }
    }
  }
}

// ---------------- launch ----------------

extern "C" void kernel_launch(void* const* d_in, const int* in_sizes, int n_in,
                              void* d_out, int out_size, void* d_ws, size_t ws_size,
                              hipStream_t stream) {
  const float* hidden = (const float*)d_in[0];
  const int*   pos    = (const int*)d_in[1];
  const float* w_qa   = (const float*)d_in[2];
  const float* q_ln   = (const float*)d_in[3];
  const float* w_qb   = (const float*)d_in[4];
  const float* w_kva  = (const float*)d_in[5];
  const float* kv_ln  = (const float*)d_in[6];
  const float* w_kvb  = (const float*)d_in[7];
  const float* w_o    = (const float*)d_in[8];
  float* out = (float*)d_out;
  char* ws = (char*)d_ws;
  (void)in_sizes; (void)n_in; (void)out_size; (void)ws_size;

  size_t off = 0;
  auto take = [&](size_t bytes) -> char* {
    char* p = ws + off;
    off = (off + bytes + 255) & ~(size_t)255;
    return p;
  };
  bf16*  hid_bf = (bf16*)take((size_t)S_LEN * HID * 2);
  bf16*  wabT   = (bf16*)take((size_t)AB_N * HID * 2);   // wqaT | wkvaT
  bf16*  wqbT   = (bf16*)take((size_t)QB_N * QL * 2);
  bf16*  wkvbT  = (bf16*)take((size_t)KVB_N * KVL * 2);
  bf16*  woT    = (bf16*)take((size_t)HID * HID * 2);
  float* qlora  = (float*)take((size_t)S_LEN * QL * 4);
  bf16*  qa_bf  = (bf16*)take((size_t)S_LEN * QL * 2);
  bf16*  qfull  = (bf16*)take((size_t)NH * S_LEN * QHD * 2);
  float* ckv    = (float*)take((size_t)S_LEN * CKV_N * 4);
  bf16*  ckv_bf = (bf16*)take((size_t)S_LEN * KVL * 2);
  float* ropc   = (float*)take((size_t)S_LEN * 16 * 4);
  float* rops   = (float*)take((size_t)S_LEN * 16 * 4);
  bf16*  kfull  = (bf16*)take((size_t)NH * S_LEN * QHD * 2);
  bf16*  vt     = (bf16*)take((size_t)NH * VD * S_LEN * 2);
  bf16*  ctx    = (bf16*)take((size_t)S_LEN * HID * 2);

  const dim3 tb(32, 8);
  cast_f32_bf16<<<(S_LEN * HID / 4 + 255) / 256, 256, 0, stream>>>(hidden, hid_bf, S_LEN * HID / 4);
  transpose_cast<<<dim3((QL + 31) / 32, (HID + 31) / 32), tb, 0, stream>>>(w_qa, wabT, HID, QL);
  transpose_cast<<<dim3((CKV_N + 31) / 32, (HID + 31) / 32), tb, 0, stream>>>(w_kva, wabT + (size_t)QL * HID, HID, CKV_N);
  transpose_cast<<<dim3((QB_N + 31) / 32, (QL + 31) / 32), tb, 0, stream>>>(w_qb, wqbT, QL, QB_N);
  transpose_cast<<<dim3((KVB_N + 31) / 32, (KVL + 31) / 32), tb, 0, stream>>>(w_kvb, wkvbT, KVL, KVB_N);
  transpose_cast<<<dim3((HID + 31) / 32, (HID + 31) / 32), tb, 0, stream>>>(w_o, woT, HID, HID);

  // fused qa|kva GEMM (544 blocks)
  gemm_qakva<<<dim3((AB_N + 63) / 64, S_LEN / 64), 256, 0, stream>>>(hid_bf, wabT, qlora, ckv);

  // kv prep (rmsnorm, rope tables, k_pe broadcast into kfull)
  kv_prep<<<S_LEN, 64, 0, stream>>>(ckv, kv_ln, pos, ckv_bf, kfull, ropc, rops);

  // q path: rmsnorm -> qb GEMM with fused rope -> qfull (960 blocks)
  rmsnorm_rows<<<S_LEN, 256, 0, stream>>>(qlora, q_ln, qa_bf, QL);
  gemm_qb_rope<<<dim3(QB_N / 64, S_LEN / 128), 256, 0, stream>>>(qa_bf, wqbT, ropc, rops, qfull);

  // kv path: kvb GEMM writes k_nope into kfull + vt transposed
  gemm_kvb_split<<<dim3(KVB_N / 128, S_LEN / 128), 256, 0, stream>>>(ckv_bf, wkvbT, kfull, vt);

  // attention (QK software-pipelined one tile ahead) + output proj
  attn_kernel<<<dim3(NH, S_LEN / 32), 64, 0, stream>>>(qfull, kfull, vt, ctx);
  gemm_out64<<<dim3(HID / 64, S_LEN / 128), 256, 0, stream>>>(ctx, woT, out);
}

// Round 21
// 225.166 us; speedup vs baseline: 1.0133x; 1.0133x over previous
//
#include <hip/hip_runtime.h>
#include <hip/hip_bf16.h>

typedef __hip_bfloat16 bf16;
typedef __attribute__((ext_vector_type(8))) __bf16 bf16x8;
typedef __attribute__((ext_vector_type(4))) __bf16 bf16x4;
typedef __attribute__((ext_vector_type(4))) float f32x4;

constexpr int S_LEN = 2048;
constexpr int HID   = 2560;
constexpr int NH    = 40;
constexpr int QL    = 768;
constexpr int KVL   = 256;
constexpr int RD    = 32;
constexpr int ND    = 64;
constexpr int VD    = 64;
constexpr int QHD   = 96;                 // NOPE_D + ROPE_D
constexpr int QB_N  = NH * QHD;           // 3840
constexpr int KVB_N = NH * (ND + VD);     // 5120
constexpr int CKV_N = KVL + RD;           // 288
constexpr int AB_N  = QL + CKV_N;         // 1056 (fused qa|kva output cols)

#define MFMA16(a, b, c) __builtin_amdgcn_mfma_f32_16x16x32_bf16((a), (b), (c), 0, 0, 0)

// position_ids may arrive as int32 or int64; values are 0..2047 so sniff layout.
__device__ __forceinline__ int get_pos(const int* pos, int s) {
  bool is64 = (pos[1] == 0 && pos[2] == 1);
  return is64 ? pos[2 * s] : pos[s];
}

// ---------------- prep ----------------

__global__ void cast_f32_bf16(const float* __restrict__ src, bf16* __restrict__ dst, int n4) {
  int i = blockIdx.x * blockDim.x + threadIdx.x;
  if (i >= n4) return;
  float4 v = reinterpret_cast<const float4*>(src)[i];
  struct { bf16 a, b, c, d; } pk;
  pk.a = __float2bfloat16(v.x); pk.b = __float2bfloat16(v.y);
  pk.c = __float2bfloat16(v.z); pk.d = __float2bfloat16(v.w);
  reinterpret_cast<uint2*>(dst)[i] = *reinterpret_cast<uint2*>(&pk);
}

// src [K][N] f32 -> dst [N][K] bf16  (B^T layout for the GEMMs)
__global__ void transpose_cast(const float* __restrict__ src, bf16* __restrict__ dst, int K, int N) {
  __shared__ float tile[32][33];
  int nb = blockIdx.x * 32, kb = blockIdx.y * 32;
  int x = threadIdx.x, y = threadIdx.y; // (32,8)
#pragma unroll
  for (int j = 0; j < 4; ++j) {
    int k = kb + y + j * 8, n = nb + x;
    tile[y + j * 8][x] = (k < K && n < N) ? src[(size_t)k * N + n] : 0.f;
  }
  __syncthreads();
#pragma unroll
  for (int j = 0; j < 4; ++j) {
    int n = nb + y + j * 8, k = kb + x;
    if (n < N && k < K) dst[(size_t)n * K + k] = __float2bfloat16(tile[x][y + j * 8]);
  }
}

// ---------------- GEMMs ----------------

// Fused qa|kva GEMM: C[2048][1056] = hid_bf * wabT^T.
// BM=64 x BN=64 tiles -> 544 blocks. 4 waves, each 16 rows x 64 cols.
__global__ __launch_bounds__(256) void gemm_qakva(const bf16* __restrict__ A,
                                                  const bf16* __restrict__ B,
                                                  float* __restrict__ q_out,
                                                  float* __restrict__ ckv_out) {
  constexpr int BM = 64, BK = 64, K = HID, N = AB_N;
  __shared__ __bf16 ldsA[BM * BK]; // 8KB
  __shared__ __bf16 ldsB[64 * BK]; // 8KB
  const int t = threadIdx.x;
  const int l = t & 63, w = t >> 6;
  const int lr = l & 15, lk = l >> 4;
  const int rowbase = blockIdx.y * BM;
  const int colbase = blockIdx.x * 64;

  f32x4 acc[4];
#pragma unroll
  for (int n = 0; n < 4; ++n) acc[n] = f32x4{0.f, 0.f, 0.f, 0.f};

  for (int kt = 0; kt < K / BK; ++kt) {
    const int kb = kt * BK;
#pragma unroll
    for (int it = 0; it < 2; ++it) {
      const int r  = it * 32 + w * 8 + (l >> 3);
      const int c8 = ((l & 7) * 8) ^ ((r & 7) << 3);
      const bf16* ga = A + (size_t)(rowbase + r) * K + kb + c8;
      __builtin_amdgcn_global_load_lds((const __attribute__((address_space(1))) void*)ga,
          (__attribute__((address_space(3))) void*)(ldsA + it * 2048 + w * 512), 16, 0, 0);
      int nrow = colbase + r;
      nrow = (nrow < N) ? nrow : (N - 1);
      const bf16* gb = B + (size_t)nrow * K + kb + c8;
      __builtin_amdgcn_global_load_lds((const __attribute__((address_space(1))) void*)gb,
          (__attribute__((address_space(3))) void*)(ldsB + it * 2048 + w * 512), 16, 0, 0);
    }
    __syncthreads();
#pragma unroll
    for (int kk = 0; kk < 2; ++kk) {
      const int arow = w * 16 + lr;
      const int ace  = (kk * 32 + lk * 8) ^ ((arow & 7) << 3);
      bf16x8 af = *(const bf16x8*)(ldsA + arow * BK + ace);
#pragma unroll
      for (int n = 0; n < 4; ++n) {
        const int row = n * 16 + lr;
        const int ce  = (kk * 32 + lk * 8) ^ ((row & 7) << 3);
        bf16x8 bfr = *(const bf16x8*)(ldsB + row * BK + ce);
        acc[n] = MFMA16(af, bfr, acc[n]);
      }
    }
    __syncthreads();
  }

#pragma unroll
  for (int n = 0; n < 4; ++n) {
    const int col = colbase + n * 16 + lr;
#pragma unroll
    for (int i = 0; i < 4; ++i) {
      const int row = rowbase + w * 16 + lk * 4 + i;
      if (col < QL)       q_out[(size_t)row * QL + col] = acc[n][i];
      else if (col < N)   ckv_out[(size_t)row * CKV_N + (col - QL)] = acc[n][i];
    }
  }
}

// Output projection: out[2048][2560] = ctx * woT^T, BM=128 x BN=64 tiles.
__global__ __launch_bounds__(256) void gemm_out64(const bf16* __restrict__ A,
                                                  const bf16* __restrict__ B,
                                                  float* __restrict__ C) {
  constexpr int BM = 128, BK = 64, K = HID, N = HID;
  __shared__ __bf16 ldsA[BM * BK];
  __shared__ __bf16 ldsB[64 * BK];
  const int t = threadIdx.x;
  const int l = t & 63, w = t >> 6;
  const int lr = l & 15, lk = l >> 4;
  const int rowbase = blockIdx.y * BM;
  const int colbase = blockIdx.x * 64;

  f32x4 acc[2][4];
#pragma unroll
  for (int m = 0; m < 2; ++m)
#pragma unroll
    for (int n = 0; n < 4; ++n) acc[m][n] = f32x4{0.f, 0.f, 0.f, 0.f};

  for (int kt = 0; kt < K / BK; ++kt) {
    const int kb = kt * BK;
#pragma unroll
    for (int it = 0; it < 4; ++it) {
      const int r  = it * 32 + w * 8 + (l >> 3);
      const int c8 = ((l & 7) * 8) ^ ((r & 7) << 3);
      const bf16* ga = A + (size_t)(rowbase + r) * K + kb + c8;
      __builtin_amdgcn_global_load_lds((const __attribute__((address_space(1))) void*)ga,
          (__attribute__((address_space(3))) void*)(ldsA + it * 2048 + w * 512), 16, 0, 0);
      if (it < 2) {
        const bf16* gb = B + (size_t)(colbase + r) * K + kb + c8;
        __builtin_amdgcn_global_load_lds((const __attribute__((address_space(1))) void*)gb,
            (__attribute__((address_space(3))) void*)(ldsB + it * 2048 + w * 512), 16, 0, 0);
      }
    }
    __syncthreads();
#pragma unroll
    for (int kk = 0; kk < 2; ++kk) {
      bf16x8 af[2], bfr[4];
#pragma unroll
      for (int m = 0; m < 2; ++m) {
        const int row = w * 32 + m * 16 + lr;
        const int ce  = (kk * 32 + lk * 8) ^ ((row & 7) << 3);
        af[m] = *(const bf16x8*)(ldsA + row * BK + ce);
      }
#pragma unroll
      for (int n = 0; n < 4; ++n) {
        const int row = n * 16 + lr;
        const int ce  = (kk * 32 + lk * 8) ^ ((row & 7) << 3);
        bfr[n] = *(const bf16x8*)(ldsB + row * BK + ce);
      }
#pragma unroll
      for (int m = 0; m < 2; ++m)
#pragma unroll
        for (int n = 0; n < 4; ++n)
          acc[m][n] = MFMA16(af[m], bfr[n], acc[m][n]);
    }
    __syncthreads();
  }

#pragma unroll
  for (int m = 0; m < 2; ++m)
#pragma unroll
    for (int n = 0; n < 4; ++n) {
      const int col = colbase + n * 16 + lr;
#pragma unroll
      for (int i = 0; i < 4; ++i) {
        const int row = rowbase + w * 32 + m * 16 + lk * 4 + i;
        C[(size_t)row * N + col] = acc[m][n][i];
      }
    }
}

// qb GEMM with fused RoPE + scale, writing qfull [NH][S][96] directly.
// BM=128 x BN=64 -> 960 blocks.
__global__ __launch_bounds__(256) void gemm_qb_rope(const bf16* __restrict__ A,
                                                    const bf16* __restrict__ B,
                                                    const float* __restrict__ ropc,
                                                    const float* __restrict__ rops,
                                                    bf16* __restrict__ qfull) {
  constexpr int BM = 128, BK = 64, K = QL;
  __shared__ __bf16 ldsA[BM * BK];
  __shared__ __bf16 ldsB[64 * BK];
  const int t = threadIdx.x;
  const int l = t & 63, w = t >> 6;
  const int lr = l & 15, lk = l >> 4;
  const int rowbase = blockIdx.y * BM;
  const int colbase = blockIdx.x * 64;
  const float scale = 0.14724444f; // 96^-0.5 * log2(e)

  f32x4 acc[2][4];
#pragma unroll
  for (int m = 0; m < 2; ++m)
#pragma unroll
    for (int n = 0; n < 4; ++n) acc[m][n] = f32x4{0.f, 0.f, 0.f, 0.f};

  for (int kt = 0; kt < K / BK; ++kt) {
    const int kb = kt * BK;
#pragma unroll
    for (int it = 0; it < 4; ++it) {
      const int r  = it * 32 + w * 8 + (l >> 3);
      const int c8 = ((l & 7) * 8) ^ ((r & 7) << 3);
      const bf16* ga = A + (size_t)(rowbase + r) * K + kb + c8;
      __builtin_amdgcn_global_load_lds((const __attribute__((address_space(1))) void*)ga,
          (__attribute__((address_space(3))) void*)(ldsA + it * 2048 + w * 512), 16, 0, 0);
      if (it < 2) {
        const bf16* gb = B + (size_t)(colbase + r) * K + kb + c8;
        __builtin_amdgcn_global_load_lds((const __attribute__((address_space(1))) void*)gb,
            (__attribute__((address_space(3))) void*)(ldsB + it * 2048 + w * 512), 16, 0, 0);
      }
    }
    __syncthreads();
#pragma unroll
    for (int kk = 0; kk < 2; ++kk) {
      bf16x8 af[2], bfr[4];
#pragma unroll
      for (int m = 0; m < 2; ++m) {
        const int row = w * 32 + m * 16 + lr;
        const int ce  = (kk * 32 + lk * 8) ^ ((row & 7) << 3);
        af[m] = *(const bf16x8*)(ldsA + row * BK + ce);
      }
#pragma unroll
      for (int n = 0; n < 4; ++n) {
        const int row = n * 16 + lr;
        const int ce  = (kk * 32 + lk * 8) ^ ((row & 7) << 3);
        bfr[n] = *(const bf16x8*)(ldsB + row * BK + ce);
      }
#pragma unroll
      for (int m = 0; m < 2; ++m)
#pragma unroll
        for (int n = 0; n < 4; ++n)
          acc[m][n] = MFMA16(af[m], bfr[n], acc[m][n]);
    }
    __syncthreads();
  }

#pragma unroll
  for (int m = 0; m < 2; ++m) {
    const int rowtop = rowbase + w * 32 + m * 16 + lk * 4;
#pragma unroll
    for (int n = 0; n < 4; ++n) {
      const int c0 = colbase + n * 16; // frag base col
      const int h  = c0 / 96;
      const int d0 = c0 - h * 96;
      const size_t qb_ = ((size_t)h * S_LEN + rowtop) * QHD + d0 + lr;
      if (d0 < ND) {
#pragma unroll
        for (int i = 0; i < 4; ++i)
          qfull[qb_ + (size_t)i * QHD] = __float2bfloat16(acc[m][n][i] * scale);
      } else if (d0 == ND) { // rope-lo: out = x0*c - x1*s, x1 = acc[m][n+1]
#pragma unroll
        for (int i = 0; i < 4; ++i) {
          const float c = ropc[(rowtop + i) * 16 + lr];
          const float s = rops[(rowtop + i) * 16 + lr];
          const float x0 = acc[m][n][i], x1 = acc[m][n + 1][i];
          qfull[qb_ + (size_t)i * QHD] = __float2bfloat16((x0 * c - x1 * s) * scale);
        }
      } else { // d0 == 80, rope-hi: out = x1*c + x0*s, x0 = acc[m][n-1]
#pragma unroll
        for (int i = 0; i < 4; ++i) {
          const float c = ropc[(rowtop + i) * 16 + lr];
          const float s = rops[(rowtop + i) * 16 + lr];
          const float x1 = acc[m][n][i], x0 = acc[m][n - 1][i];
          qfull[qb_ + (size_t)i * QHD] = __float2bfloat16((x1 * c + x0 * s) * scale);
        }
      }
    }
  }
}

// kvb GEMM writing k_nope into kfull[h][s][0:64] (stride 96) and vt [NH][64][S].
__global__ __launch_bounds__(256) void gemm_kvb_split(const bf16* __restrict__ A,
                                                      const bf16* __restrict__ B,
                                                      bf16* __restrict__ kfull,
                                                      bf16* __restrict__ vt) {
  constexpr int BM = 128, BN = 128, BK = 64, K = KVL;
  __shared__ __bf16 ldsA[BM * BK];
  __shared__ __bf16 ldsB[BN * BK];
  const int t = threadIdx.x;
  const int l = t & 63, w = t >> 6;
  const int lr = l & 15, lk = l >> 4;
  const int wr = w >> 1, wc = w & 1;
  const int rowbase = blockIdx.y * BM;
  const int h = blockIdx.x; // head == col tile
  const int colbase = h * BN;

  f32x4 acc[4][4];
#pragma unroll
  for (int m = 0; m < 4; ++m)
#pragma unroll
    for (int n = 0; n < 4; ++n) acc[m][n] = f32x4{0.f, 0.f, 0.f, 0.f};

  for (int kt = 0; kt < K / BK; ++kt) {
    const int kb = kt * BK;
#pragma unroll
    for (int it = 0; it < 4; ++it) {
      const int r  = it * 32 + w * 8 + (l >> 3);
      const int c8 = ((l & 7) * 8) ^ ((r & 7) << 3);
      const bf16* ga = A + (size_t)(rowbase + r) * K + kb + c8;
      __builtin_amdgcn_global_load_lds((const __attribute__((address_space(1))) void*)ga,
          (__attribute__((address_space(3))) void*)(ldsA + it * 2048 + w * 512), 16, 0, 0);
      const bf16* gb = B + (size_t)(colbase + r) * K + kb + c8;
      __builtin_amdgcn_global_load_lds((const __attribute__((address_space(1))) void*)gb,
          (__attribute__((address_space(3))) void*)(ldsB + it * 2048 + w * 512), 16, 0, 0);
    }
    __syncthreads();
#pragma unroll
    for (int kk = 0; kk < 2; ++kk) {
      bf16x8 af[4], bfr[4];
#pragma unroll
      for (int m = 0; m < 4; ++m) {
        const int row = wr * 64 + m * 16 + lr;
        const int ce  = (kk * 32 + lk * 8) ^ ((row & 7) << 3);
        af[m] = *(const bf16x8*)(ldsA + row * BK + ce);
      }
#pragma unroll
      for (int n = 0; n < 4; ++n) {
        const int row = wc * 64 + n * 16 + lr;
        const int ce  = (kk * 32 + lk * 8) ^ ((row & 7) << 3);
        bfr[n] = *(const bf16x8*)(ldsB + row * BK + ce);
      }
#pragma unroll
      for (int m = 0; m < 4; ++m)
#pragma unroll
        for (int n = 0; n < 4; ++n)
          acc[m][n] = MFMA16(af[m], bfr[n], acc[m][n]);
    }
    __syncthreads();
  }

#pragma unroll
  for (int m = 0; m < 4; ++m) {
    const int rowtop = rowbase + wr * 64 + m * 16 + lk * 4;
    if (wc == 0) { // k_nope -> kfull[h][s][0:64] (stride QHD)
#pragma unroll
      for (int n = 0; n < 4; ++n) {
        const int d = n * 16 + lr;
#pragma unroll
        for (int i = 0; i < 4; ++i)
          kfull[((size_t)h * S_LEN + rowtop + i) * QHD + d] = __float2bfloat16(acc[m][n][i]);
      }
    } else {        // V -> vt[h][64][S] (8B transposed stores, L2 merges)
#pragma unroll
      for (int n = 0; n < 4; ++n) {
        const int d = n * 16 + lr;
        bf16x4 pk;
#pragma unroll
        for (int i = 0; i < 4; ++i) pk[i] = (__bf16)acc[m][n][i];
        *(bf16x4*)(vt + ((size_t)h * VD + d) * S_LEN + rowtop) = pk;
      }
    }
  }
}

// ---------------- norms / prep ----------------

__global__ void rmsnorm_rows(const float* __restrict__ in, const float* __restrict__ w,
                             bf16* __restrict__ out, int C) {
  const int r = blockIdx.x;
  const float* row = in + (size_t)r * C;
  float ss = 0.f;
  for (int c = threadIdx.x; c < C; c += 256) { float v = row[c]; ss += v * v; }
#pragma unroll
  for (int d = 32; d > 0; d >>= 1) ss += __shfl_xor(ss, d);
  __shared__ float red[4];
  if ((threadIdx.x & 63) == 0) red[threadIdx.x >> 6] = ss;
  __syncthreads();
  const float tot = red[0] + red[1] + red[2] + red[3];
  const float rs = rsqrtf(tot / (float)C + 1e-6f);
  for (int c = threadIdx.x; c < C; c += 256)
    out[(size_t)r * C + c] = __float2bfloat16(row[c] * rs * w[c]);
}

// per row: rmsnorm(ckv[0:256]) -> bf16 ; rope(k_pe) broadcast into
// kfull[h][s][64:96] for ALL heads (via LDS); rope tables for the q path.
__global__ void kv_prep(const float* __restrict__ ckv, const float* __restrict__ w,
                        const int* __restrict__ pos, bf16* __restrict__ ckv_bf,
                        bf16* __restrict__ kfull, float* __restrict__ ropc,
                        float* __restrict__ rops) {
  const int s = blockIdx.x, t = threadIdx.x; // 64 threads
  __shared__ bf16 pe_lds[32];
  const float* row = ckv + (size_t)s * CKV_N;
  float v[4]; float ss = 0.f;
#pragma unroll
  for (int j = 0; j < 4; ++j) { v[j] = row[t + 64 * j]; ss += v[j] * v[j]; }
#pragma unroll
  for (int d = 32; d > 0; d >>= 1) ss += __shfl_xor(ss, d);
  const float rs = rsqrtf(ss / (float)KVL + 1e-6f);
#pragma unroll
  for (int j = 0; j < 4; ++j)
    ckv_bf[(size_t)s * KVL + t + 64 * j] = __float2bfloat16(v[j] * rs * w[t + 64 * j]);
  if (t < 16) {
    const float x0 = row[KVL + t], x1 = row[KVL + 16 + t];
    const float p = (float)get_pos(pos, s);
    const float invf = exp2f(-(float)t * (13.2877124f / 16.f)); // 10000^(-t/16)
    const float ang = p * invf, c = cosf(ang), sn = sinf(ang);
    ropc[s * 16 + t] = c;
    rops[s * 16 + t] = sn;
    pe_lds[t]      = __float2bfloat16(x0 * c - x1 * sn);
    pe_lds[16 + t] = __float2bfloat16(x1 * c + x0 * sn);
  }
  __syncthreads();
  // broadcast pe into every head's kfull row (coalesced 64B per 32-lane group)
  for (int idx = t; idx < NH * 32; idx += 64) {
    const int h = idx >> 5, d = idx & 31;
    kfull[((size_t)h * S_LEN + s) * QHD + ND + d] = pe_lds[d];
  }
}

// ---------------- causal flash attention ----------------
// One wave per block, 32 q rows, KVBLK=64, SWAPPED QK^T (st = mfma(K,Q)),
// log2-domain softmax, shuffle-free steady state (lane-local defer gate +
// lane-partial l), XOR-swizzled P tile. K and V for tile n+1 issued at the
// top of tile n (V double-buffered in regs). Grid (NH, 64), q-tiles REVERSED.
__global__ __launch_bounds__(64) void attn_kernel(const bf16* __restrict__ qfull,
                                                  const bf16* __restrict__ kfull,
                                                  const bf16* __restrict__ vt,
                                                  bf16* __restrict__ ctx) {
  const int h = blockIdx.x;
  const int qw = ((int)gridDim.y - 1 - (int)blockIdx.y) * 32;
  const int l = threadIdx.x;
  const int lr = l & 15, lk = l >> 4;
  const bf16* Q  = qfull + (size_t)h * S_LEN * QHD;
  const bf16* Kf = kfull + (size_t)h * S_LEN * QHD;
  const bf16* V  = vt + (size_t)h * VD * S_LEN;
  __shared__ __bf16 plds[32][64]; // XOR-swizzled: col ^= (lr&7)<<3

  bf16x8 qf[2][3];
#pragma unroll
  for (int qg = 0; qg < 2; ++qg)
#pragma unroll
    for (int ks = 0; ks < 3; ++ks)
      qf[qg][ks] = *(const bf16x8*)(Q + (size_t)(qw + qg * 16 + lr) * QHD + ks * 32 + lk * 8);

  f32x4 o[2][4];
  float mrow[2], lrow[2]; // lrow is LANE-PARTIAL
#pragma unroll
  for (int qg = 0; qg < 2; ++qg) {
#pragma unroll
    for (int dt = 0; dt < 4; ++dt) o[qg][dt] = f32x4{0.f, 0.f, 0.f, 0.f};
    mrow[qg] = -1e30f; lrow[qg] = 0.f;
  }

  // preload K tile 0 and V tile 0
  bf16x8 kf[4][3];
#pragma unroll
  for (int sub = 0; sub < 4; ++sub)
#pragma unroll
    for (int ks = 0; ks < 3; ++ks)
      kf[sub][ks] = *(const bf16x8*)(Kf + (size_t)(sub * 16 + lr) * QHD + ks * 32 + lk * 8);
  bf16x8 vA[2][4];
#pragma unroll
  for (int h2 = 0; h2 < 2; ++h2)
#pragma unroll
    for (int dt = 0; dt < 4; ++dt)
      vA[h2][dt] = *(const bf16x8*)(V + (size_t)(dt * 16 + lr) * S_LEN + h2 * 32 + lk * 8);

  for (int kb = 0;; kb += 64) {
    const int nkb = kb + 64;
    const bool more = (nkb <= qw);

    // issue NEXT tile's V loads first (whole tile of cover)
    bf16x8 vB[2][4];
    if (more) {
#pragma unroll
      for (int h2 = 0; h2 < 2; ++h2)
#pragma unroll
        for (int dt = 0; dt < 4; ++dt)
          vB[h2][dt] = *(const bf16x8*)(V + (size_t)(dt * 16 + lr) * S_LEN + nkb + h2 * 32 + lk * 8);
    }

    // S^T tile: st[qg][sub][i] = S[q = qw+qg*16+lr][k = kb+sub*16+lk*4+i]
    f32x4 st[2][4];
#pragma unroll
    for (int qg = 0; qg < 2; ++qg)
#pragma unroll
      for (int sub = 0; sub < 4; ++sub) st[qg][sub] = f32x4{0.f, 0.f, 0.f, 0.f};
    __builtin_amdgcn_s_setprio(1);
#pragma unroll
    for (int qg = 0; qg < 2; ++qg)
#pragma unroll
      for (int sub = 0; sub < 4; ++sub)
#pragma unroll
        for (int ks = 0; ks < 3; ++ks)
          st[qg][sub] = MFMA16(kf[sub][ks], qf[qg][ks], st[qg][sub]);
    __builtin_amdgcn_s_setprio(0);

    // issue NEXT tile's K loads (rest-of-tile cover)
    if (more) {
#pragma unroll
      for (int sub = 0; sub < 4; ++sub)
#pragma unroll
        for (int ks = 0; ks < 3; ++ks)
          kf[sub][ks] = *(const bf16x8*)(Kf + (size_t)(nkb + sub * 16 + lr) * QHD + ks * 32 + lk * 8);
    }

    const bool diag = !more;
    float lmax[2];
#pragma unroll
    for (int qg = 0; qg < 2; ++qg) {
      const int q = qw + qg * 16 + lr;
      if (diag) {
#pragma unroll
        for (int sub = 0; sub < 4; ++sub)
#pragma unroll
          for (int i = 0; i < 4; ++i)
            if (kb + sub * 16 + lk * 4 + i > q) st[qg][sub][i] = -1e30f;
      }
      float m0 = -1e30f;
#pragma unroll
      for (int sub = 0; sub < 4; ++sub)
#pragma unroll
        for (int i = 0; i < 4; ++i) m0 = fmaxf(m0, st[qg][sub][i]);
      lmax[qg] = m0; // lane-local max (NOT reduced)
    }

    // defer-rescale gate on lane-local maxima (== global-max check via __all)
    const bool noresc = __all((lmax[0] <= mrow[0] + 8.f) && (lmax[1] <= mrow[1] + 8.f));
    float mnew[2], fac[2];
    if (noresc) {
      mnew[0] = mrow[0]; mnew[1] = mrow[1];
    } else { // rare path: full cross-lane reduce + rescale factors
#pragma unroll
      for (int qg = 0; qg < 2; ++qg) {
        float t0 = lmax[qg];
        t0 = fmaxf(t0, __shfl_xor(t0, 16));
        t0 = fmaxf(t0, __shfl_xor(t0, 32));
        mnew[qg] = fmaxf(mrow[qg], t0);
        fac[qg] = exp2f(mrow[qg] - mnew[qg]);
        mrow[qg] = mnew[qg];
      }
    }

#pragma unroll
    for (int qg = 0; qg < 2; ++qg) {
      float ts = 0.f;
#pragma unroll
      for (int sub = 0; sub < 4; ++sub) {
        bf16x4 pk;
#pragma unroll
        for (int i = 0; i < 4; ++i) {
          const float p = exp2f(st[qg][sub][i] - mnew[qg]);
          ts += p;
          pk[i] = (__bf16)p;
        }
        const int swc = (sub * 16 + lk * 4) ^ ((lr & 7) << 3);
        *(bf16x4*)(&plds[qg * 16 + lr][swc]) = pk;
      }
      if (noresc) lrow[qg] += ts;
      else        lrow[qg] = lrow[qg] * fac[qg] + ts;
    }
    if (!noresc) {
#pragma unroll
      for (int qg = 0; qg < 2; ++qg)
#pragma unroll
        for (int i = 0; i < 4; ++i) {
          const float fr = __shfl(fac[qg], lk * 4 + i);
#pragma unroll
          for (int dt = 0; dt < 4; ++dt) o[qg][dt][i] *= fr;
        }
    }

    // PV: A = P from LDS (swizzled read), B = V frags prefetched LAST tile
#pragma unroll
    for (int h2 = 0; h2 < 2; ++h2) {
      const int swc = (h2 * 32 + lk * 8) ^ ((lr & 7) << 3);
      bf16x8 pa0 = *(const bf16x8*)(&plds[lr][swc]);
      bf16x8 pa1 = *(const bf16x8*)(&plds[16 + lr][swc]);
      __builtin_amdgcn_s_setprio(1);
#pragma unroll
      for (int dt = 0; dt < 4; ++dt) {
        o[0][dt] = MFMA16(pa0, vA[h2][dt], o[0][dt]);
        o[1][dt] = MFMA16(pa1, vA[h2][dt], o[1][dt]);
      }
      __builtin_amdgcn_s_setprio(0);
    }
    if (!more) break;
    // rotate V buffers
#pragma unroll
    for (int h2 = 0; h2 < 2; ++h2)
#pragma unroll
      for (int dt = 0; dt < 4; ++dt) vA[h2][dt] = vB[h2][dt];
  }

  // epilogue: reduce lane-partial l (once), broadcast 1/l to o-row owners
#pragma unroll
  for (int qg = 0; qg < 2; ++qg) {
    float ls = lrow[qg];
    ls += __shfl_xor(ls, 16);
    ls += __shfl_xor(ls, 32);
    const float linv = 1.0f / ls;
#pragma unroll
    for (int i = 0; i < 4; ++i) {
      const float inv = __shfl(linv, lk * 4 + i);
#pragma unroll
      for (int dt = 0; dt < 4; ++dt) {
        const int row = qw + qg * 16 + lk * 4 + i;
        const int col = h * VD + dt * 16 + lr;
        ctx[(size_t)row * HID + col] = __float2bfloat16(o[qg][dt][i] * inv);
      }
    }
  }
}

// ---------------- launch ----------------

extern "C" void kernel_launch(void* const* d_in, const int* in_sizes, int n_in,
                              void* d_out, int out_size, void* d_ws, size_t ws_size,
                              hipStream_t stream) {
  const float* hidden = (const float*)d_in[0];
  const int*   pos    = (const int*)d_in[1];
  const float* w_qa   = (const float*)d_in[2];
  const float* q_ln   = (const float*)d_in[3];
  const float* w_qb   = (const float*)d_in[4];
  const float* w_kva  = (const float*)d_in[5];
  const float* kv_ln  = (const float*)d_in[6];
  const float* w_kvb  = (const float*)d_in[7];
  const float* w_o    = (const float*)d_in[8];
  float* out = (float*)d_out;
  char* ws = (char*)d_ws;
  (void)in_sizes; (void)n_in; (void)out_size; (void)ws_size;

  size_t off = 0;
  auto take = [&](size_t bytes) -> char* {
    char* p = ws + off;
    off = (off + bytes + 255) & ~(size_t)255;
    return p;
  };
  bf16*  hid_bf = (bf16*)take((size_t)S_LEN * HID * 2);
  bf16*  wabT   = (bf16*)take((size_t)AB_N * HID * 2);   // wqaT | wkvaT
  bf16*  wqbT   = (bf16*)take((size_t)QB_N * QL * 2);
  bf16*  wkvbT  = (bf16*)take((size_t)KVB_N * KVL * 2);
  bf16*  woT    = (bf16*)take((size_t)HID * HID * 2);
  float* qlora  = (float*)take((size_t)S_LEN * QL * 4);
  bf16*  qa_bf  = (bf16*)take((size_t)S_LEN * QL * 2);
  bf16*  qfull  = (bf16*)take((size_t)NH * S_LEN * QHD * 2);
  float* ckv    = (float*)take((size_t)S_LEN * CKV_N * 4);
  bf16*  ckv_bf = (bf16*)take((size_t)S_LEN * KVL * 2);
  float* ropc   = (float*)take((size_t)S_LEN * 16 * 4);
  float* rops   = (float*)take((size_t)S_LEN * 16 * 4);
  bf16*  kfull  = (bf16*)take((size_t)NH * S_LEN * QHD * 2);
  bf16*  vt     = (bf16*)take((size_t)NH * VD * S_LEN * 2);
  bf16*  ctx    = (bf16*)take((size_t)S_LEN * HID * 2);

  const dim3 tb(32, 8);
  cast_f32_bf16<<<(S_LEN * HID / 4 + 255) / 256, 256, 0, stream>>>(hidden, hid_bf, S_LEN * HID / 4);
  transpose_cast<<<dim3((QL + 31) / 32, (HID + 31) / 32), tb, 0, stream>>>(w_qa, wabT, HID, QL);
  transpose_cast<<<dim3((CKV_N + 31) / 32, (HID + 31) / 32), tb, 0, stream>>>(w_kva, wabT + (size_t)QL * HID, HID, CKV_N);
  transpose_cast<<<dim3((QB_N + 31) / 32, (QL + 31) / 32), tb, 0, stream>>>(w_qb, wqbT, QL, QB_N);
  transpose_cast<<<dim3((KVB_N + 31) / 32, (KVL + 31) / 32), tb, 0, stream>>>(w_kvb, wkvbT, KVL, KVB_N);
  transpose_cast<<<dim3((HID + 31) / 32, (HID + 31) / 32), tb, 0, stream>>>(w_o, woT, HID, HID);

  // fused qa|kva GEMM (544 blocks)
  gemm_qakva<<<dim3((AB_N + 63) / 64, S_LEN / 64), 256, 0, stream>>>(hid_bf, wabT, qlora, ckv);

  // kv prep (rmsnorm, rope tables, k_pe broadcast into kfull)
  kv_prep<<<S_LEN, 64, 0, stream>>>(ckv, kv_ln, pos, ckv_bf, kfull, ropc, rops);

  // q path: rmsnorm -> qb GEMM with fused rope -> qfull (960 blocks)
  rmsnorm_rows<<<S_LEN, 256, 0, stream>>>(qlora, q_ln, qa_bf, QL);
  gemm_qb_rope<<<dim3(QB_N / 64, S_LEN / 128), 256, 0, stream>>>(qa_bf, wqbT, ropc, rops, qfull);

  // kv path: kvb GEMM writes k_nope into kfull + vt transposed
  gemm_kvb_split<<<dim3(KVB_N / 128, S_LEN / 128), 256, 0, stream>>>(ckv_bf, wkvbT, kfull, vt);

  // attention + output proj
  attn_kernel<<<dim3(NH, S_LEN / 32), 64, 0, stream>>>(qfull, kfull, vt, ctx);
  gemm_out64<<<dim3(HID / 64, S_LEN / 128), 256, 0, stream>>>(ctx, woT, out);
}